// Round 6
// baseline (141.187 us; speedup 1.0000x reference)
//
#include <hip/hip_runtime.h>

// B=1024, D=1024 -> tokens N_TOK=4096, EMB=256, CODES=512.
// d_out (float32): out[1048576], loss[1], idx_as_float[4096].

typedef _Float16 half8 __attribute__((ext_vector_type(8)));
typedef _Float16 half4 __attribute__((ext_vector_type(4)));
typedef float floatx4 __attribute__((ext_vector_type(4)));

#define LO_SCALE 2048.0f
#define INV_LO_SCALE (1.0f / 2048.0f)

// ---------------------------------------------------------------------------
// k-interleaved storage (validated r2-r5): within each 64-k group, element k
// sits at pos(k) = (k&32) | ((k&12)<<1) | ((k&16)>>2) | (k&3), so MFMA frag
// (ks,fg) = halves {ks*32+4fg+j, ks*32+16+4fg+j} is one 16B chunk ks*4+fg.
// ---------------------------------------------------------------------------
__device__ __forceinline__ int remap4(int k0)
{
    return (k0 & 32) | ((k0 & 12) << 1) | ((k0 & 16) >> 2);
}
__device__ __forceinline__ int remap1(int k)
{
    return (k & ~63) | (k & 32) | ((k & 12) << 1) | ((k & 16) >> 2) | (k & 3);
}

__device__ __forceinline__ void gl_lds16(const _Float16* g, _Float16* l)
{
    __builtin_amdgcn_global_load_lds(
        (const __attribute__((address_space(1))) void*)g,
        (__attribute__((address_space(3))) void*)l, 16, 0, 0);
}

// LDS row = 64 halves = 8 chunks of 16B; stored chunk p holds global chunk
// p^(row&7) (staging pre-XORs the global source; DMA write stays linear).
__device__ __forceinline__ half8 rfrag(const _Float16* m, int row, int ks, int fg)
{
    const int ch = ((ks << 2) + fg) ^ (row & 7);
    return *reinterpret_cast<const half8*>(&m[(row << 6) + (ch << 3)]);
}

// ---------------------------------------------------------------------------
// C = act(A @ B^T + bias), fp16 3-term split emulating fp32.
// A: h/l [M][K], B: h/l [N][K], k-interleaved f16.
// 256 thr / 4 waves; block tile 64x64; wave tile 32x32 (2x2 of 16x16x32).
// Wave w stages matrix w (Ah,Al,Bh,Bl) via global_load_lds, double-buffered.
// ARGMIN: instead of writing C, emit per-block partial argmin of
//   d = -2*C + cnorm[col] over the block's 64 cols -> pv/pi[cb][4096].
// ---------------------------------------------------------------------------
template <bool RELU, bool WSPLIT, bool ARGMIN>
__global__ __launch_bounds__(256) void gemm_k(
    const _Float16* __restrict__ Ah, const _Float16* __restrict__ Al,
    const _Float16* __restrict__ Bh, const _Float16* __restrict__ Bl,
    const float* __restrict__ bias,
    _Float16* __restrict__ Ch, _Float16* __restrict__ Cl,
    const float* __restrict__ cnorm, float* __restrict__ pv, int* __restrict__ pi,
    int N, int K)
{
    __shared__ __align__(16) _Float16 sm[2][4][4096];   // 64KB -> 2 blocks/CU

    const int tid = threadIdx.x;
    const int m0 = blockIdx.y * 64, n0 = blockIdx.x * 64;
    const int w = tid >> 6, lane = tid & 63;
    const int srow = lane >> 3, sc = lane & 7;

    // staging: wave w owns matrix w entirely (8 gl_lds of 8 rows each)
    const _Float16* gsrc = (w == 0) ? Ah : (w == 1) ? Al : (w == 2) ? Bh : Bl;
    const int rb0 = (w < 2) ? m0 : n0;
    const size_t gbase = (size_t)(rb0 + srow) * K + ((sc ^ srow) << 3);

    // compute: 2x2 wave grid, 32x32 tile each
    const int wm = (w & 1) * 32, wn = (w >> 1) * 32;
    const int fr = lane & 15, fg = lane >> 4;

    floatx4 hh[2][2] = {};
    floatx4 c1[2][2] = {};   // Ah*Bl
    floatx4 c2[2][2] = {};   // Al*Bh

    const int NT = K >> 6;

    auto STAGE = [&](int buf, int t) {
        const size_t kb = (size_t)(t << 6);
        #pragma unroll
        for (int j = 0; j < 8; ++j)
            gl_lds16(gsrc + gbase + (size_t)(j << 3) * K + kb,
                     &sm[buf][w][(j << 3) << 6]);
    };

    STAGE(0, 0);
    __syncthreads();

    for (int t = 0; t < NT; ++t) {
        const int cur = t & 1;
        if (t + 1 < NT) STAGE(cur ^ 1, t + 1);   // prefetch under compute
        #pragma unroll
        for (int ks = 0; ks < 2; ++ks) {
            half8 a_h[2], a_l[2], b_h[2], b_l[2];
            #pragma unroll
            for (int i = 0; i < 2; ++i) {
                a_h[i] = rfrag(sm[cur][0], wm + (i << 4) + fr, ks, fg);
                a_l[i] = rfrag(sm[cur][1], wm + (i << 4) + fr, ks, fg);
                b_h[i] = rfrag(sm[cur][2], wn + (i << 4) + fr, ks, fg);
                b_l[i] = rfrag(sm[cur][3], wn + (i << 4) + fr, ks, fg);
            }
            #pragma unroll
            for (int i = 0; i < 2; ++i)
                #pragma unroll
                for (int j = 0; j < 2; ++j) {
                    hh[i][j] = __builtin_amdgcn_mfma_f32_16x16x32_f16(a_h[i], b_h[j], hh[i][j], 0, 0, 0);
                    c1[i][j] = __builtin_amdgcn_mfma_f32_16x16x32_f16(a_h[i], b_l[j], c1[i][j], 0, 0, 0);
                    c2[i][j] = __builtin_amdgcn_mfma_f32_16x16x32_f16(a_l[i], b_h[j], c2[i][j], 0, 0, 0);
                }
        }
        __syncthreads();   // drains vmcnt -> next buf staged & cur safe to reuse
    }

    if (!ARGMIN) {
        // C/D layout (validated): col = lane&15, row = 4*(lane>>4) + reg.
        #pragma unroll
        for (int j = 0; j < 2; ++j) {
            const int col = n0 + wn + (j << 4) + fr;
            const float bv = bias ? bias[col] : 0.0f;
            const int colr = remap1(col);
            #pragma unroll
            for (int i = 0; i < 2; ++i)
                #pragma unroll
                for (int r = 0; r < 4; ++r) {
                    const int row = m0 + wm + (i << 4) + (fg << 2) + r;
                    float v = hh[i][j][r] + (c1[i][j][r] + c2[i][j][r]) * INV_LO_SCALE + bv;
                    if (RELU) v = fmaxf(v, 0.0f);
                    if (WSPLIT) {
                        const size_t o = (size_t)row * N + colr;
                        const _Float16 hi = (_Float16)v;
                        Ch[o] = hi;
                        Cl[o] = (_Float16)((v - (float)hi) * LO_SCALE);
                    }
                }
        }
    } else {
        // partial argmin over this block's 64 codes
        const int cA = n0 + wn + fr, cB = cA + 16;
        const float cnA = cnorm[cA], cnB = cnorm[cB];
        float* cv = (float*)&sm[0][0][0];
        int* ci = (int*)(cv + 128);
        #pragma unroll
        for (int i = 0; i < 2; ++i)
            #pragma unroll
            for (int r = 0; r < 4; ++r) {
                const float v0 = hh[i][0][r] + (c1[i][0][r] + c2[i][0][r]) * INV_LO_SCALE;
                const float v1 = hh[i][1][r] + (c1[i][1][r] + c2[i][1][r]) * INV_LO_SCALE;
                const float d0 = fmaf(-2.0f, v0, cnA);
                const float d1 = fmaf(-2.0f, v1, cnB);
                float d = d0; int di = cA;
                if (d1 < d0) { d = d1; di = cB; }      // tie keeps lower col
                #pragma unroll
                for (int msk = 1; msk <= 8; msk <<= 1) {
                    const float ov = __shfl_xor(d, msk);
                    const int oi = __shfl_xor(di, msk);
                    if (ov < d || (ov == d && oi < di)) { d = ov; di = oi; }
                }
                if (fr == 0) {
                    const int rl = (i << 4) + (fg << 2) + r;
                    cv[w * 32 + rl] = d;
                    ci[w * 32 + rl] = di;
                }
            }
        __syncthreads();
        if (tid < 64) {
            const int a = tid >> 5, rl = tid & 31;
            float d = cv[a * 32 + rl]; int di = ci[a * 32 + rl];       // wn=0 half
            const float d2 = cv[(a + 2) * 32 + rl];
            const int i2 = ci[(a + 2) * 32 + rl];                     // wn=32 half
            if (d2 < d || (d2 == d && i2 < di)) { d = d2; di = i2; }
            pv[blockIdx.x * 4096 + m0 + tid] = d;
            pi[blockIdx.x * 4096 + m0 + tid] = di;
        }
    }
}

// ---------------------------------------------------------------------------
// Fused prep (unchanged r5): b<768 weight splitT; b<1280 obs split; else CB.
// ---------------------------------------------------------------------------
__global__ __launch_bounds__(256) void prep_kernel(
    const float* __restrict__ W1, const float* __restrict__ W2,
    const float* __restrict__ W3, const float* __restrict__ obs,
    const float* __restrict__ CB,
    _Float16* __restrict__ T1h, _Float16* __restrict__ T1l,
    _Float16* __restrict__ T2h, _Float16* __restrict__ T2l,
    _Float16* __restrict__ T3h, _Float16* __restrict__ T3l,
    _Float16* __restrict__ Oh, _Float16* __restrict__ Ol,
    _Float16* __restrict__ CBh, _Float16* __restrict__ CBl,
    float* __restrict__ cnorm)
{
    __shared__ float tile[64][65];
    const int b = blockIdx.x, tid = threadIdx.x;

    if (b < 768) {
        const int z = b >> 8, rem = b & 255;
        const float* Wm = (z == 0) ? W1 : (z == 1) ? W2 : W3;
        _Float16* Th = (z == 0) ? T1h : (z == 1) ? T2h : T3h;
        _Float16* Tl = (z == 0) ? T1l : (z == 1) ? T2l : T3l;
        const int nb = (rem & 15) * 64, kb = (rem >> 4) * 64;
        {
            const int kr = tid >> 2, c0 = (tid & 3) * 16;
            #pragma unroll
            for (int c = 0; c < 16; c += 4) {
                float4 v = *reinterpret_cast<const float4*>(
                    &Wm[(size_t)(kb + kr) * 1024 + nb + c0 + c]);
                tile[kr][c0 + c] = v.x; tile[kr][c0 + c + 1] = v.y;
                tile[kr][c0 + c + 2] = v.z; tile[kr][c0 + c + 3] = v.w;
            }
        }
        __syncthreads();
        {
            const int nr = tid >> 2, k0 = (tid & 3) * 16;
            #pragma unroll
            for (int g = 0; g < 4; ++g) {
                const int kk = k0 + g * 4;
                half4 h, lo;
                #pragma unroll
                for (int j = 0; j < 4; ++j) {
                    const float x = tile[kk + j][nr];
                    const _Float16 hi = (_Float16)x;
                    h[j] = hi;
                    lo[j] = (_Float16)((x - (float)hi) * LO_SCALE);
                }
                const size_t o = (size_t)(nb + nr) * 1024 + kb + remap4(kk);
                *reinterpret_cast<half4*>(&Th[o]) = h;
                *reinterpret_cast<half4*>(&Tl[o]) = lo;
            }
        }
    } else if (b < 1280) {
        const size_t e0 = ((size_t)(b - 768) * 256 + tid) * 8;
        float4 a = *reinterpret_cast<const float4*>(&obs[e0]);
        float4 c = *reinterpret_cast<const float4*>(&obs[e0 + 4]);
        float xs[8] = {a.x, a.y, a.z, a.w, c.x, c.y, c.z, c.w};
        half4 h[2], lo[2];
        #pragma unroll
        for (int q = 0; q < 2; ++q)
            #pragma unroll
            for (int j = 0; j < 4; ++j) {
                const float x = xs[q * 4 + j];
                const _Float16 hi = (_Float16)x;
                h[q][j] = hi;
                lo[q][j] = (_Float16)((x - (float)hi) * LO_SCALE);
            }
        const size_t base = e0 & ~(size_t)63;
        const int r1 = remap4((int)(e0 & 63));
        const int r2 = remap4((int)((e0 + 4) & 63));
        *reinterpret_cast<half4*>(&Oh[base + r1]) = h[0];
        *reinterpret_cast<half4*>(&Oh[base + r2]) = h[1];
        *reinterpret_cast<half4*>(&Ol[base + r1]) = lo[0];
        *reinterpret_cast<half4*>(&Ol[base + r2]) = lo[1];
    } else {
        const int wv = tid >> 6, lane = tid & 63;
        const int code = (b - 1280) * 4 + wv;
        const int k0 = lane * 4;
        float4 c = *reinterpret_cast<const float4*>(&CB[(size_t)code * 256 + k0]);
        float xs[4] = {c.x, c.y, c.z, c.w};
        half4 h, lo;
        float s = 0.f;
        #pragma unroll
        for (int j = 0; j < 4; ++j) {
            const _Float16 hi = (_Float16)xs[j];
            h[j] = hi;
            lo[j] = (_Float16)((xs[j] - (float)hi) * LO_SCALE);
            s += xs[j] * xs[j];
        }
        const size_t o = (size_t)code * 256 + (k0 & ~63) + remap4(k0 & 63);
        *reinterpret_cast<half4*>(&CBh[o]) = h;
        *reinterpret_cast<half4*>(&CBl[o]) = lo;
        #pragma unroll
        for (int off = 32; off; off >>= 1) s += __shfl_down(s, off);
        if (lane == 0) cnorm[code] = s;
    }
}

// ---------------------------------------------------------------------------
// vq-lite: reduce 8 argmin candidates/token, gather code, loss partial.
// One wave per token; 8 tokens / 512-thr block.
// ---------------------------------------------------------------------------
__global__ __launch_bounds__(512) void vq_lite_kernel(
    const float* __restrict__ pv, const int* __restrict__ pi,
    const _Float16* __restrict__ Fh, const _Float16* __restrict__ Fl,
    const float* __restrict__ CB,
    float* __restrict__ out, float* __restrict__ pl, float* __restrict__ idx_out)
{
    const int wid = threadIdx.x >> 6, lane = threadIdx.x & 63;
    const int n = blockIdx.x * 8 + wid;

    float best = 3.4e38f;
    int bidx = 0x7fffffff;
    if (lane < 8) { best = pv[lane * 4096 + n]; bidx = pi[lane * 4096 + n]; }
    #pragma unroll
    for (int msk = 1; msk <= 4; msk <<= 1) {
        const float ov = __shfl_xor(best, msk);
        const int oi = __shfl_xor(bidx, msk);
        if (ov < best || (ov == best && oi < bidx)) { best = ov; bidx = oi; }
    }
    bidx = __shfl(bidx, 0);
    best = __shfl(best, 0);

    // ||z||^2 (k-interleave is a row permutation -> sum invariant)
    const int base = n * 256 + lane * 4;
    half4 h4 = *reinterpret_cast<const half4*>(&Fh[base]);
    half4 l4 = *reinterpret_cast<const half4*>(&Fl[base]);
    float zn = 0.f;
    #pragma unroll
    for (int j = 0; j < 4; ++j) {
        const float z = (float)h4[j] + (float)l4[j] * INV_LO_SCALE;
        zn = fmaf(z, z, zn);
    }
    #pragma unroll
    for (int off = 32; off; off >>= 1) zn += __shfl_down(zn, off);

    float4 q4 = *reinterpret_cast<const float4*>(&CB[(size_t)bidx * 256 + lane * 4]);
    *reinterpret_cast<float4*>(&out[(size_t)n * 256 + lane * 4]) = q4;

    __shared__ float part[8];
    if (lane == 0) {
        part[wid] = zn + best;          // = ||z - q||^2 for this token
        idx_out[n] = (float)bidx;
    }
    __syncthreads();
    if (threadIdx.x == 0) {
        float s = 0.f;
        #pragma unroll
        for (int i = 0; i < 8; ++i) s += part[i];
        pl[blockIdx.x] = s;
    }
}

__global__ __launch_bounds__(512) void finalize_kernel(
    const float* __restrict__ pl, float* __restrict__ loss_out)
{
    float s = pl[threadIdx.x];
    #pragma unroll
    for (int off = 32; off; off >>= 1) s += __shfl_down(s, off);
    __shared__ float p[8];
    if ((threadIdx.x & 63) == 0) p[threadIdx.x >> 6] = s;
    __syncthreads();
    if (threadIdx.x == 0) {
        float t = 0.f;
        #pragma unroll
        for (int i = 0; i < 8; ++i) t += p[i];
        loss_out[0] = 1.25f * t / 1048576.0f;
    }
}

// ---------------------------------------------------------------------------
extern "C" void kernel_launch(void* const* d_in, const int* in_sizes, int n_in,
                              void* d_out, int out_size, void* d_ws, size_t ws_size,
                              hipStream_t stream)
{
    const float* obs = (const float*)d_in[0];
    const float* W1  = (const float*)d_in[1];
    const float* b1  = (const float*)d_in[2];
    const float* W2  = (const float*)d_in[3];
    const float* b2  = (const float*)d_in[4];
    const float* W3  = (const float*)d_in[5];
    const float* b3  = (const float*)d_in[6];
    const float* CB  = (const float*)d_in[7];

    float* out = (float*)d_out;
    float* loss_out = out + 1048576;
    float* idx_out  = out + 1048577;

    char* Wp = (char*)d_ws;
    _Float16* Oh    = (_Float16*)(Wp + (0u  << 20));
    _Float16* Ol    = (_Float16*)(Wp + (2u  << 20));
    _Float16* W1t_h = (_Float16*)(Wp + (4u  << 20));
    _Float16* W1t_l = (_Float16*)(Wp + (6u  << 20));
    _Float16* W2t_h = (_Float16*)(Wp + (8u  << 20));
    _Float16* W2t_l = (_Float16*)(Wp + (10u << 20));
    _Float16* W3t_h = (_Float16*)(Wp + (12u << 20));
    _Float16* W3t_l = (_Float16*)(Wp + (14u << 20));
    _Float16* H1_h  = (_Float16*)(Wp + (16u << 20));
    _Float16* H1_l  = (_Float16*)(Wp + (18u << 20));
    _Float16* H2_h  = (_Float16*)(Wp + (20u << 20));
    _Float16* H2_l  = (_Float16*)(Wp + (22u << 20));
    _Float16* F_h   = (_Float16*)(Wp + (24u << 20));
    _Float16* F_l   = (_Float16*)(Wp + (26u << 20));
    _Float16* CB_h  = (_Float16*)(Wp + (28u << 20));
    _Float16* CB_l  = (_Float16*)(Wp + (28u << 20) + 512 * 256 * 2);
    float*    cn    = (float*)(Wp + (28u << 20) + 2 * 512 * 256 * 2);
    float*    pv    = (float*)(Wp + (29u << 20));          // 8*4096 f32
    int*      pi    = (int*)(Wp + (30u << 20));            // 8*4096 i32
    float*    pl    = (float*)(Wp + (31u << 20));          // 512 f32

    prep_kernel<<<1408, 256, 0, stream>>>(
        W1, W2, W3, obs, CB,
        W1t_h, W1t_l, W2t_h, W2t_l, W3t_h, W3t_l,
        Oh, Ol, CB_h, CB_l, cn);

    gemm_k<true, true, false><<<dim3(16, 16), 256, 0, stream>>>(
        Oh, Ol, W1t_h, W1t_l, b1, H1_h, H1_l, nullptr, nullptr, nullptr, 1024, 1024);
    gemm_k<true, true, false><<<dim3(16, 16), 256, 0, stream>>>(
        H1_h, H1_l, W2t_h, W2t_l, b2, H2_h, H2_l, nullptr, nullptr, nullptr, 1024, 1024);
    gemm_k<false, true, false><<<dim3(16, 16), 256, 0, stream>>>(
        H2_h, H2_l, W3t_h, W3t_l, b3, F_h, F_l, nullptr, nullptr, nullptr, 1024, 1024);

    // S-distances + per-block partial argmin: grid (codes/64=8, tokens/64=64)
    gemm_k<false, false, true><<<dim3(8, 64), 256, 0, stream>>>(
        F_h, F_l, CB_h, CB_l, nullptr, nullptr, nullptr, cn, pv, pi, 512, 256);

    vq_lite_kernel<<<512, 512, 0, stream>>>(pv, pi, F_h, F_l, CB, out, pl, idx_out);
    finalize_kernel<<<1, 512, 0, stream>>>(pl, loss_out);
}